// Round 14
// baseline (122.994 us; speedup 1.0000x reference)
//
#include <hip/hip_runtime.h>
#include <stdint.h>

// Problem constants
#define Bb 4
#define Nn 2048
#define Dd 512
#define Hh 8
#define BN 8192   // Bb*Nn

typedef __attribute__((ext_vector_type(4))) float f32x4;
typedef __attribute__((ext_vector_type(8))) short s16x8;

// Q pre-scale: 1/sqrt(DK) * log2(e) so QK^T lands in log2 domain directly
#define QSCALE 0.1803368801111204f

// ---- workspace layout (bytes) ----
static constexpr size_t OFF_XB    = 1024;                                   // 8192x512 bf16
static constexpr size_t OFF_WQKVT = OFF_XB    + (size_t)2 * BN * Dd;        // 1536x512 bf16
static constexpr size_t OFF_WOUTT = OFF_WQKVT + (size_t)2 * 3 * Dd * Dd;    // 512x512 bf16
static constexpr size_t OFF_MASKP = OFF_WOUTT + (size_t)2 * Dd * Dd;        // B*N*32 u64
static constexpr size_t OFF_Q     = OFF_MASKP + (size_t)8 * Bb * Nn * (Nn / 64); // (B,H,N,64) bf16
static constexpr size_t OFF_K     = OFF_Q     + (size_t)2 * BN * Dd;
static constexpr size_t OFF_VT    = OFF_K     + (size_t)2 * BN * Dd;        // (B,H,64,N) bf16
static constexpr size_t OFF_AO    = OFF_VT    + (size_t)2 * BN * Dd;        // (B,N,512) bf16

__device__ inline unsigned short f2bf(float f) {
  union { float f; unsigned int u; } v; v.f = f;
  const unsigned int u = v.u;
  return (unsigned short)((u + 0x7fffu + ((u >> 16) & 1u)) >> 16);  // RNE
}

__device__ inline float exp2_hw(float x) {
  float r;
  asm("v_exp_f32 %0, %1" : "=v"(r) : "v"(x));
  return r;
}

__device__ inline unsigned int cvtpk_bf16(float lo, float hi) {
  unsigned int r;
  asm("v_cvt_pk_bf16_f32 %0, %1, %2" : "=v"(r) : "v"(lo), "v"(hi));
  return r;
}

__device__ inline void gload16(const void* g, void* l) {
  __builtin_amdgcn_global_load_lds(
      (const __attribute__((address_space(1))) uint32_t*)g,
      (__attribute__((address_space(3))) uint32_t*)l, 16, 0, 0);
}

// ---- fused prep: x->bf16 | LDS-tiled W transposes | mask bitpack ----
__global__ void prep_kernel(const float* __restrict__ x, unsigned short* __restrict__ xb,
                            const float* __restrict__ Wqkv, unsigned short* __restrict__ wqkvT,
                            const float* __restrict__ Wout, unsigned short* __restrict__ woutT,
                            const unsigned char* __restrict__ mb, const int* __restrict__ mi,
                            unsigned long long* __restrict__ mp) {
  __shared__ float tsm[64][65];
  const int bid = blockIdx.x, tid = threadIdx.x;
  if (bid < 2048) {
    // x (fp32) -> xb (bf16), coalesced both sides
    for (int i = bid * 256 + tid; i < BN * Dd / 4; i += 2048 * 256) {
      const float4 v = ((const float4*)x)[i];
      ushort4 o;
      o.x = f2bf(v.x); o.y = f2bf(v.y); o.z = f2bf(v.z); o.w = f2bf(v.w);
      ((ushort4*)xb)[i] = o;
    }
  } else if (bid < 2304) {
    // 64x64 LDS-tiled transpose: W (RxC f32) -> WT (CxR bf16), coalesced R+W
    const float* W; unsigned short* WT; int C, tt;
    if (bid < 2240) { W = Wqkv; WT = wqkvT; C = 1536; tt = bid - 2048; }
    else            { W = Wout; WT = woutT; C = 512;  tt = bid - 2240; }
    const int tcols = C >> 6;
    const int rt = tt / tcols, ct = tt - rt * tcols;
    const int r0 = rt * 64, c0t = ct * 64;
    {
      const int row = tid >> 4, colq = tid & 15;
#pragma unroll
      for (int rr = 0; rr < 4; ++rr) {
        const float4 v = *(const float4*)&W[(size_t)(r0 + rr * 16 + row) * C + c0t + colq * 4];
        tsm[rr * 16 + row][colq * 4 + 0] = v.x;
        tsm[rr * 16 + row][colq * 4 + 1] = v.y;
        tsm[rr * 16 + row][colq * 4 + 2] = v.z;
        tsm[rr * 16 + row][colq * 4 + 3] = v.w;
      }
    }
    __syncthreads();
    {
      const int ocl = tid >> 2, seg = tid & 3;
      unsigned short ob[16];
#pragma unroll
      for (int j = 0; j < 16; ++j) ob[j] = f2bf(tsm[seg * 16 + j][ocl]);
      unsigned short* dst = WT + (size_t)(c0t + ocl) * 512 + r0 + seg * 16;
      *(s16x8*)dst = *(s16x8*)ob;
      *(s16x8*)(dst + 8) = *(s16x8*)(ob + 8);
    }
  } else {
    // mask bitpack: word w holds keys [w*64, w*64+64). Byte-vs-int32 storage
    // detected from the guaranteed-True diagonal (4B storage lands 3/4 of the
    // probed byte offsets on upper bytes -> 0).
    const int lane = tid & 63;
    const int ok = mb[(size_t)(lane + 1) * (Nn + 1)] != 0;
    const int bytemode = (__ballot(ok) == 0xFFFFFFFFFFFFFFFFull);
    const int nwords = Bb * Nn * (Nn / 64);                 // 262144
    int gw = ((bid - 2304) * 256 + tid) >> 6;
    for (; gw < nwords; gw += 1024 * 4) {
      const size_t idx = (size_t)gw * 64 + lane;
      int v;
      if (bytemode) v = mb[idx]; else v = mi[idx];          // real branch: no OOB speculation
      const unsigned long long bits = __ballot(v != 0);
      if (lane == 0) mp[gw] = bits;
    }
  }
}

// ---- 128xBNt bf16 TN GEMM core, K=512, BK=64, double-buffered LDS ----
// 1-D grid with XCD-chunked swizzle (bijective: grid = 8 xcd * 8 lx * NY).
// MODE 0 (BNt=128): epilogue scatters Q (pre-scaled), K (B,H,N,64) direct
//   (32B runs); V tiles (c0>=1024) re-tiled via LDS -> coalesced 16B writes.
// MODE 1 (BNt=64): epilogue adds bias, LeakyReLU, stores fp32.
template <int MODE, int BNt>
__global__ __launch_bounds__(256, 2) void gemm128(
    const unsigned short* __restrict__ A,   // M x 512 bf16, k-contig
    const unsigned short* __restrict__ BT,  // Ncols x 512 bf16, k-contig
    unsigned short* __restrict__ qb, unsigned short* __restrict__ kb,
    unsigned short* __restrict__ vt, const float* __restrict__ bias,
    float* __restrict__ outp) {
  constexpr int JN = BNt / 32;              // n-fragments per wave
  constexpr int BBYTES = BNt * 128;         // per-buffer B bytes (BNt rows x 64k x 2B)
  __shared__ char smem[32768 + 2 * BBYTES];
  const int tid = threadIdx.x;
  const int lane = tid & 63, wv = tid >> 6;
  const int g = lane >> 4, n16 = lane & 15;
  const int bid = blockIdx.x;
  const int xcd = bid & 7, tt = bid >> 3;
  const int gx = xcd * 8 + (tt & 7);        // x-tile 0..63
  const int gy = tt >> 3;                   // y-tile
  const int m0 = gx * 128;
  const int c0 = gy * BNt;
  const int wm = wv >> 1, wn = wv & 1;   // 2x2 waves

  f32x4 acc[4][JN] = {};

  auto stage = [&](int buf, int t) {
#pragma unroll
    for (int j = 0; j < 4; ++j) {          // A: 128 rows x 64 k
      const int base = (wv * 4 + j) * 1024;
      const int o = base + lane * 16;
      const int r = o >> 7;
      const int sl = ((o >> 4) & 7) ^ (r & 7);
      gload16(A + (size_t)(m0 + r) * 512 + t * 64 + sl * 8, smem + buf * 16384 + base);
    }
#pragma unroll
    for (int j = 0; j < BNt / 32; ++j) {   // B: BNt rows x 64 k
      const int base = (wv * (BNt / 32) + j) * 1024;
      const int o = base + lane * 16;
      const int r = o >> 7;
      const int sl = ((o >> 4) & 7) ^ (r & 7);
      gload16(BT + (size_t)(c0 + r) * 512 + t * 64 + sl * 8, smem + 32768 + buf * BBYTES + base);
    }
  };

  stage(0, 0);
  __syncthreads();
  int cur = 0;
  for (int t = 0; t < 8; ++t) {
    if (t < 7) stage(cur ^ 1, t + 1);
    const unsigned short* Ab = (const unsigned short*)(smem + cur * 16384);
    const unsigned short* Bbuf = (const unsigned short*)(smem + 32768 + cur * BBYTES);
    s16x8 af[4][2], bfr[JN][2];
#pragma unroll
    for (int f = 0; f < 4; ++f)
#pragma unroll
      for (int kc = 0; kc < 2; ++kc) {
        const int rr = wm * 64 + f * 16 + n16;
        const int sl = kc * 4 + g;
        af[f][kc] = *(const s16x8*)&Ab[(rr * 128 + ((sl ^ (rr & 7)) * 16)) / 2];
      }
#pragma unroll
    for (int f = 0; f < JN; ++f)
#pragma unroll
      for (int kc = 0; kc < 2; ++kc) {
        const int cc = wn * (BNt / 2) + f * 16 + n16;
        const int sl = kc * 4 + g;
        bfr[f][kc] = *(const s16x8*)&Bbuf[(cc * 128 + ((sl ^ (cc & 7)) * 16)) / 2];
      }
    __builtin_amdgcn_s_setprio(1);
#pragma unroll
    for (int i = 0; i < 4; ++i)
#pragma unroll
      for (int jn = 0; jn < JN; ++jn) {
        acc[i][jn] = __builtin_amdgcn_mfma_f32_16x16x32_bf16(af[i][0], bfr[jn][0], acc[i][jn], 0, 0, 0);
        acc[i][jn] = __builtin_amdgcn_mfma_f32_16x16x32_bf16(af[i][1], bfr[jn][1], acc[i][jn], 0, 0, 0);
      }
    __builtin_amdgcn_s_setprio(0);
    __syncthreads();
    cur ^= 1;
  }

  if (MODE == 0) {
    const int bq = m0 >> 11, nn0 = m0 & 2047;
    if (c0 < 1024) {
      // Q or K: per-lane 2B stores in 32B runs (16 consecutive dk)
#pragma unroll
      for (int i = 0; i < 4; ++i) {
        const int tl0 = wm * 64 + i * 16 + g * 4;
#pragma unroll
        for (int jn = 0; jn < JN; ++jn) {
          const int c = c0 + wn * 64 + jn * 16 + n16;
          if (c < 512) {
            const int h = c >> 6, dk = c & 63;
            unsigned short* qp = qb + (((size_t)bq * 8 + h) * 2048 + nn0 + tl0) * 64 + dk;
#pragma unroll
            for (int r = 0; r < 4; ++r) qp[(size_t)r * 64] = f2bf(acc[i][jn][r] * QSCALE);
          } else {
            const int c2 = c - 512, h = c2 >> 6, dk = c2 & 63;
            unsigned short* kp = kb + (((size_t)bq * 8 + h) * 2048 + nn0 + tl0) * 64 + dk;
#pragma unroll
            for (int r = 0; r < 4; ++r) kp[(size_t)r * 64] = f2bf(acc[i][jn][r]);
          }
        }
      }
    } else {
      // V: re-tile through LDS -> coalesced 16B writes of V^T (B,H,64,N)
      constexpr int SW = 136;   // ushort stride (272B: 16B-aligned rows, bank-spread)
      unsigned short* Ep = (unsigned short*)smem;
#pragma unroll
      for (int i = 0; i < 4; ++i) {
        const int tl0 = wm * 64 + i * 16 + g * 4;
#pragma unroll
        for (int jn = 0; jn < JN; ++jn) {
          const int cl = wn * 64 + jn * 16 + n16;
          ushort4 pk;
          pk.x = f2bf(acc[i][jn][0]); pk.y = f2bf(acc[i][jn][1]);
          pk.z = f2bf(acc[i][jn][2]); pk.w = f2bf(acc[i][jn][3]);
          *(ushort4*)&Ep[cl * SW + (tl0 ^ (((cl >> 3) & 7) << 3))] = pk;
        }
      }
      __syncthreads();
#pragma unroll
      for (int itc = 0; itc < 8; ++itc) {
        const int chunk = itc * 256 + tid;
        const int cl = chunk >> 4, tc = chunk & 15;
        const s16x8 v = *(const s16x8*)&Ep[cl * SW + ((tc * 8) ^ (((cl >> 3) & 7) << 3))];
        const int c2 = c0 + cl - 1024;
        const int h = c2 >> 6, dk = c2 & 63;
        *(s16x8*)(vt + (((size_t)bq * 8 + h) * 64 + dk) * 2048 + nn0 + tc * 8) = v;
      }
    }
  } else {
#pragma unroll
    for (int jn = 0; jn < JN; ++jn) {
      const int c = c0 + wn * (BNt / 2) + jn * 16 + n16;
      const float bc = bias[c];
#pragma unroll
      for (int i = 0; i < 4; ++i) {
        const int tok0 = m0 + wm * 64 + i * 16 + g * 4;
#pragma unroll
        for (int r = 0; r < 4; ++r) {
          float v = acc[i][jn][r] + bc;
          v = v >= 0.f ? v : 0.1f * v;               // LeakyReLU
          outp[(size_t)(tok0 + r) * 512 + c] = v;
        }
      }
    }
  }
}

// ---- flash attention: 4 waves, each owning TWO 16-row q-groups (32 q/wave,
// QBLK=128). kf/vf LDS reads are q-independent -> each read feeds two MFMAs
// (A-group + B-group), cutting LDS bytes per q-row by ~43%. All fragment
// paths identical to the verified round-8 structure, just duplicated.
// No softmax stabilizer (log2-domain scores, diagonal keeps l>0).
__global__ __launch_bounds__(256, 3) void attn_kernel(
    const unsigned short* __restrict__ qb, const unsigned short* __restrict__ kb,
    const unsigned short* __restrict__ vt, const unsigned long long* __restrict__ mp,
    unsigned short* __restrict__ ao) {
  __shared__ unsigned short Kl[2][4096];  // [m 64][k 64] (swizzled slots)
  __shared__ unsigned short Vl[2][4096];  // [dk 64][m 64]
  __shared__ unsigned short Pl[8][1024];  // [wv*2+grp]: [n 16][m 64]
  const int tid = threadIdx.x, lane = tid & 63, wv = tid >> 6;
  const int g = lane >> 4, n16 = lane & 15;
  // XCD-aware swizzle: 512 blocks, 8 XCDs -> 64 contiguous logical blocks per
  // XCD = 4 (b,h) groups, K/V (512KB/head) resident in its private L2.
  const int sbid = (blockIdx.x & 7) * 64 + (blockIdx.x >> 3);
  const int qt = sbid & 15, bh = sbid >> 4;
  const int b = bh >> 3, h = bh & 7;
  const int n0A = qt * 128 + wv * 16;   // group A rows
  const int n0B = n0A + 64;             // group B rows
  const unsigned short* Qh = qb + (size_t)bh * 2048 * 64;
  const unsigned short* Kh = kb + (size_t)bh * 2048 * 64;
  const unsigned short* Vh = vt + (size_t)bh * 64 * 2048;
  const unsigned long long* mrowA = mp + ((size_t)b * 2048 + n0A + n16) * 32;
  const unsigned long long* mrowB = mp + ((size_t)b * 2048 + n0B + n16) * 32;

  // Q fragments (B-operand of swapped QK^T): row n=lane&15, k-contig, pre-scaled
  const s16x8 qfA0 = *(const s16x8*)&Qh[(size_t)(n0A + n16) * 64 + g * 8];
  const s16x8 qfA1 = *(const s16x8*)&Qh[(size_t)(n0A + n16) * 64 + 32 + g * 8];
  const s16x8 qfB0 = *(const s16x8*)&Qh[(size_t)(n0B + n16) * 64 + g * 8];
  const s16x8 qfB1 = *(const s16x8*)&Qh[(size_t)(n0B + n16) * 64 + 32 + g * 8];

  const s16x8 ones = {0x3F80, 0x3F80, 0x3F80, 0x3F80, 0x3F80, 0x3F80, 0x3F80, 0x3F80};

  f32x4 ofA[4] = {}, ofB[4] = {};
  f32x4 accA = {}, accB = {};

  unsigned short* PwA = Pl[wv * 2];
  unsigned short* PwB = Pl[wv * 2 + 1];
  // hoisted P LDS byte offsets (XOR-swizzled)
  int pwo[4], pro[2];
#pragma unroll
  for (int mf = 0; mf < 4; ++mf) {
    int bo = n16 * 128 + mf * 32 + g * 8;
    pwo[mf] = bo ^ ((n16 & 7) << 4);
  }
#pragma unroll
  for (int kc = 0; kc < 2; ++kc) {
    int bo = n16 * 128 + kc * 64 + g * 16;
    pro[kc] = bo ^ ((n16 & 7) << 4);
  }

  auto stage = [&](int buf, int m0) {
#pragma unroll
    for (int j = 0; j < 2; ++j) {
      const int base = (wv * 2 + j) * 1024;       // wave-uniform LDS byte base
      const int o = base + lane * 16;
      const int r = o >> 7;
      const int sl = ((o >> 4) & 7) ^ (r & 7);    // pre-swizzled logical slot
      gload16(Kh + (size_t)(m0 + r) * 64 + sl * 8, (char*)&Kl[buf][0] + base);
      gload16(Vh + (size_t)r * 2048 + m0 + sl * 8, (char*)&Vl[buf][0] + base);
    }
  };

  // p = exp2(s) masked via sbfe sign-mask AND, packed to bf16 pairs
  auto packP = [&](unsigned long long wb, const f32x4* sc, unsigned int* w) {
    const unsigned int wlo = (unsigned int)(wb >> (g * 4));
    const unsigned int whi = (unsigned int)(wb >> (32 + g * 4));
#pragma unroll
    for (int mf = 0; mf < 4; ++mf) {
      const unsigned int wsel = ((mf & 2) ? whi : wlo) >> ((mf & 1) * 16);
      float p[4];
#pragma unroll
      for (int r = 0; r < 4; ++r) {
        const unsigned int sm = (unsigned int)__builtin_amdgcn_sbfe((int)wsel, r, 1);
        const float pv = exp2_hw(sc[mf][r]);
        p[r] = __uint_as_float(__float_as_uint(pv) & sm);
      }
      w[mf * 2]     = cvtpk_bf16(p[0], p[1]);
      w[mf * 2 + 1] = cvtpk_bf16(p[2], p[3]);
    }
  };

  stage(0, 0);
  unsigned long long wbitsA = mrowA[0], wbitsB = mrowB[0];
  __syncthreads();    // drains vmcnt before any wave reads the tile
  int cur = 0;
  for (int it = 0; it < 32; ++it) {
    if (it < 31) stage(cur ^ 1, (it + 1) * 64);
    const unsigned long long wnextA = (it < 31) ? mrowA[it + 1] : 0ull;
    const unsigned long long wnextB = (it < 31) ? mrowB[it + 1] : 0ull;

    // S^T = K · Q for both q-groups: each kf read feeds 2 MFMAs
    f32x4 scA[4] = {}, scB[4] = {};
    __builtin_amdgcn_s_setprio(1);
#pragma unroll
    for (int mf = 0; mf < 4; ++mf) {
      const int ml = mf * 16 + n16;
#pragma unroll
      for (int kc = 0; kc < 2; ++kc) {
        const int sl = kc * 4 + g;
        const s16x8 kf = *(const s16x8*)&Kl[cur][(ml * 128 + ((sl ^ (ml & 7)) * 16)) / 2];
        scA[mf] = __builtin_amdgcn_mfma_f32_16x16x32_bf16(kf, kc ? qfA1 : qfA0, scA[mf], 0, 0, 0);
        scB[mf] = __builtin_amdgcn_mfma_f32_16x16x32_bf16(kf, kc ? qfB1 : qfB0, scB[mf], 0, 0, 0);
      }
    }
    __builtin_amdgcn_s_setprio(0);

    unsigned int wA[8], wB[8];
    packP(wbitsA, scA, wA);
    packP(wbitsB, scB, wB);

    // P^T -> per-group LDS (swizzled), re-fragment as PV A-operand
#pragma unroll
    for (int mf = 0; mf < 4; ++mf) {
      uint2 pkA; pkA.x = wA[mf * 2]; pkA.y = wA[mf * 2 + 1];
      *(uint2*)((char*)PwA + pwo[mf]) = pkA;
      uint2 pkB; pkB.x = wB[mf * 2]; pkB.y = wB[mf * 2 + 1];
      *(uint2*)((char*)PwB + pwo[mf]) = pkB;
    }
    __builtin_amdgcn_s_setprio(1);
#pragma unroll
    for (int kc = 0; kc < 2; ++kc) {
      const s16x8 pfA = *(const s16x8*)((const char*)PwA + pro[kc]);
      const s16x8 pfB = *(const s16x8*)((const char*)PwB + pro[kc]);
      accA = __builtin_amdgcn_mfma_f32_16x16x32_bf16(pfA, ones, accA, 0, 0, 0);  // l-sum A
      accB = __builtin_amdgcn_mfma_f32_16x16x32_bf16(pfB, ones, accB, 0, 0, 0);  // l-sum B
#pragma unroll
      for (int df = 0; df < 4; ++df) {
        const int dk = df * 16 + n16;
        const int sl = kc * 4 + g;
        const s16x8 vf = *(const s16x8*)&Vl[cur][(dk * 128 + ((sl ^ (dk & 7)) * 16)) / 2];
        ofA[df] = __builtin_amdgcn_mfma_f32_16x16x32_bf16(pfA, vf, ofA[df], 0, 0, 0);
        ofB[df] = __builtin_amdgcn_mfma_f32_16x16x32_bf16(pfB, vf, ofB[df], 0, 0, 0);
      }
    }
    __builtin_amdgcn_s_setprio(0);
    wbitsA = wnextA; wbitsB = wnextB;
    __syncthreads();   // drains staged loads for buffer cur^1 + guards overwrite
    cur ^= 1;
  }

  float rinvA[4], rinvB[4];
#pragma unroll
  for (int r = 0; r < 4; ++r) { rinvA[r] = 1.f / accA[r]; rinvB[r] = 1.f / accB[r]; }
#pragma unroll
  for (int df = 0; df < 4; ++df)
#pragma unroll
    for (int r = 0; r < 4; ++r) {
      const int tokA = b * 2048 + n0A + 4 * g + r;
      ao[(size_t)tokA * 512 + h * 64 + df * 16 + n16] = f2bf(ofA[df][r] * rinvA[r]);
      const int tokB = b * 2048 + n0B + 4 * g + r;
      ao[(size_t)tokB * 512 + h * 64 + df * 16 + n16] = f2bf(ofB[df][r] * rinvB[r]);
    }
}

extern "C" void kernel_launch(void* const* d_in, const int* in_sizes, int n_in,
                              void* d_out, int out_size, void* d_ws, size_t ws_size,
                              hipStream_t stream) {
  const float* x = (const float*)d_in[0];
  const void* mask = d_in[1];
  const float* Wqkv = (const float*)d_in[2];
  const float* Wout = (const float*)d_in[3];
  const float* bout = (const float*)d_in[4];
  float* out = (float*)d_out;
  char* ws = (char*)d_ws;

  unsigned short* xb = (unsigned short*)(ws + OFF_XB);
  unsigned short* wqkvT = (unsigned short*)(ws + OFF_WQKVT);
  unsigned short* woutT = (unsigned short*)(ws + OFF_WOUTT);
  unsigned long long* mp = (unsigned long long*)(ws + OFF_MASKP);
  unsigned short* qb = (unsigned short*)(ws + OFF_Q);
  unsigned short* kb = (unsigned short*)(ws + OFF_K);
  unsigned short* vt = (unsigned short*)(ws + OFF_VT);
  unsigned short* ao = (unsigned short*)(ws + OFF_AO);

  prep_kernel<<<3328, 256, 0, stream>>>(x, xb, Wqkv, wqkvT, Wout, woutT,
                                        (const unsigned char*)mask, (const int*)mask, mp);
  gemm128<0, 128><<<768, 256, 0, stream>>>(xb, wqkvT, qb, kb, vt, nullptr, nullptr);
  attn_kernel<<<512, 256, 0, stream>>>(qb, kb, vt, mp, ao);
  gemm128<1, 64><<<512, 256, 0, stream>>>(ao, woutT, nullptr, nullptr, nullptr, bout, out);
}

// Round 15
// 116.064 us; speedup vs baseline: 1.0597x; 1.0597x over previous
//
#include <hip/hip_runtime.h>
#include <stdint.h>

// Problem constants
#define Bb 4
#define Nn 2048
#define Dd 512
#define Hh 8
#define BN 8192   // Bb*Nn

typedef __attribute__((ext_vector_type(4))) float f32x4;
typedef __attribute__((ext_vector_type(8))) short s16x8;

// Q pre-scale: 1/sqrt(DK) * log2(e) so QK^T lands in log2 domain directly
#define QSCALE 0.1803368801111204f

// ---- workspace layout (bytes) ----
static constexpr size_t OFF_XB    = 1024;                                   // 8192x512 bf16
static constexpr size_t OFF_WQKVT = OFF_XB    + (size_t)2 * BN * Dd;        // 1536x512 bf16
static constexpr size_t OFF_WOUTT = OFF_WQKVT + (size_t)2 * 3 * Dd * Dd;    // 512x512 bf16
static constexpr size_t OFF_MASKP = OFF_WOUTT + (size_t)2 * Dd * Dd;        // B*N*32 u64
static constexpr size_t OFF_Q     = OFF_MASKP + (size_t)8 * Bb * Nn * (Nn / 64); // (B,H,N,64) bf16
static constexpr size_t OFF_K     = OFF_Q     + (size_t)2 * BN * Dd;
static constexpr size_t OFF_VT    = OFF_K     + (size_t)2 * BN * Dd;        // (B,H,64,N) bf16
static constexpr size_t OFF_AO    = OFF_VT    + (size_t)2 * BN * Dd;        // (B,N,512) bf16

__device__ inline unsigned short f2bf(float f) {
  union { float f; unsigned int u; } v; v.f = f;
  const unsigned int u = v.u;
  return (unsigned short)((u + 0x7fffu + ((u >> 16) & 1u)) >> 16);  // RNE
}

__device__ inline float exp2_hw(float x) {
  float r;
  asm("v_exp_f32 %0, %1" : "=v"(r) : "v"(x));
  return r;
}

__device__ inline unsigned int cvtpk_bf16(float lo, float hi) {
  unsigned int r;
  asm("v_cvt_pk_bf16_f32 %0, %1, %2" : "=v"(r) : "v"(lo), "v"(hi));
  return r;
}

__device__ inline void gload16(const void* g, void* l) {
  __builtin_amdgcn_global_load_lds(
      (const __attribute__((address_space(1))) uint32_t*)g,
      (__attribute__((address_space(3))) uint32_t*)l, 16, 0, 0);
}

// ---- fused prep: x->bf16 | LDS-tiled W transposes | mask bitpack ----
__global__ void prep_kernel(const float* __restrict__ x, unsigned short* __restrict__ xb,
                            const float* __restrict__ Wqkv, unsigned short* __restrict__ wqkvT,
                            const float* __restrict__ Wout, unsigned short* __restrict__ woutT,
                            const unsigned char* __restrict__ mb, const int* __restrict__ mi,
                            unsigned long long* __restrict__ mp) {
  __shared__ float tsm[64][65];
  const int bid = blockIdx.x, tid = threadIdx.x;
  if (bid < 2048) {
    // x (fp32) -> xb (bf16), coalesced both sides
    for (int i = bid * 256 + tid; i < BN * Dd / 4; i += 2048 * 256) {
      const float4 v = ((const float4*)x)[i];
      ushort4 o;
      o.x = f2bf(v.x); o.y = f2bf(v.y); o.z = f2bf(v.z); o.w = f2bf(v.w);
      ((ushort4*)xb)[i] = o;
    }
  } else if (bid < 2304) {
    // 64x64 LDS-tiled transpose: W (RxC f32) -> WT (CxR bf16), coalesced R+W
    const float* W; unsigned short* WT; int C, tt;
    if (bid < 2240) { W = Wqkv; WT = wqkvT; C = 1536; tt = bid - 2048; }
    else            { W = Wout; WT = woutT; C = 512;  tt = bid - 2240; }
    const int tcols = C >> 6;
    const int rt = tt / tcols, ct = tt - rt * tcols;
    const int r0 = rt * 64, c0t = ct * 64;
    {
      const int row = tid >> 4, colq = tid & 15;
#pragma unroll
      for (int rr = 0; rr < 4; ++rr) {
        const float4 v = *(const float4*)&W[(size_t)(r0 + rr * 16 + row) * C + c0t + colq * 4];
        tsm[rr * 16 + row][colq * 4 + 0] = v.x;
        tsm[rr * 16 + row][colq * 4 + 1] = v.y;
        tsm[rr * 16 + row][colq * 4 + 2] = v.z;
        tsm[rr * 16 + row][colq * 4 + 3] = v.w;
      }
    }
    __syncthreads();
    {
      const int ocl = tid >> 2, seg = tid & 3;
      unsigned short ob[16];
#pragma unroll
      for (int j = 0; j < 16; ++j) ob[j] = f2bf(tsm[seg * 16 + j][ocl]);
      unsigned short* dst = WT + (size_t)(c0t + ocl) * 512 + r0 + seg * 16;
      *(s16x8*)dst = *(s16x8*)ob;
      *(s16x8*)(dst + 8) = *(s16x8*)(ob + 8);
    }
  } else {
    // mask bitpack: word w holds keys [w*64, w*64+64). Byte-vs-int32 storage
    // detected from the guaranteed-True diagonal (4B storage lands 3/4 of the
    // probed byte offsets on upper bytes -> 0).
    const int lane = tid & 63;
    const int ok = mb[(size_t)(lane + 1) * (Nn + 1)] != 0;
    const int bytemode = (__ballot(ok) == 0xFFFFFFFFFFFFFFFFull);
    const int nwords = Bb * Nn * (Nn / 64);                 // 262144
    int gw = ((bid - 2304) * 256 + tid) >> 6;
    for (; gw < nwords; gw += 1024 * 4) {
      const size_t idx = (size_t)gw * 64 + lane;
      int v;
      if (bytemode) v = mb[idx]; else v = mi[idx];          // real branch: no OOB speculation
      const unsigned long long bits = __ballot(v != 0);
      if (lane == 0) mp[gw] = bits;
    }
  }
}

// ---- 128xBNt bf16 TN GEMM core, K=512, BK=64, double-buffered LDS ----
// 1-D grid with XCD-chunked swizzle (bijective: grid = 8 xcd * 8 lx * NY).
// MODE 0 (BNt=128): epilogue scatters Q (pre-scaled), K (B,H,N,64) direct
//   (32B runs); V tiles (c0>=1024) re-tiled via LDS -> coalesced 16B writes.
// MODE 1 (BNt=64): epilogue adds bias, LeakyReLU, stores fp32.
template <int MODE, int BNt>
__global__ __launch_bounds__(256, 2) void gemm128(
    const unsigned short* __restrict__ A,   // M x 512 bf16, k-contig
    const unsigned short* __restrict__ BT,  // Ncols x 512 bf16, k-contig
    unsigned short* __restrict__ qb, unsigned short* __restrict__ kb,
    unsigned short* __restrict__ vt, const float* __restrict__ bias,
    float* __restrict__ outp) {
  constexpr int JN = BNt / 32;              // n-fragments per wave
  constexpr int BBYTES = BNt * 128;         // per-buffer B bytes (BNt rows x 64k x 2B)
  __shared__ char smem[32768 + 2 * BBYTES];
  const int tid = threadIdx.x;
  const int lane = tid & 63, wv = tid >> 6;
  const int g = lane >> 4, n16 = lane & 15;
  const int bid = blockIdx.x;
  const int xcd = bid & 7, tt = bid >> 3;
  const int gx = xcd * 8 + (tt & 7);        // x-tile 0..63
  const int gy = tt >> 3;                   // y-tile
  const int m0 = gx * 128;
  const int c0 = gy * BNt;
  const int wm = wv >> 1, wn = wv & 1;   // 2x2 waves

  f32x4 acc[4][JN] = {};

  auto stage = [&](int buf, int t) {
#pragma unroll
    for (int j = 0; j < 4; ++j) {          // A: 128 rows x 64 k
      const int base = (wv * 4 + j) * 1024;
      const int o = base + lane * 16;
      const int r = o >> 7;
      const int sl = ((o >> 4) & 7) ^ (r & 7);
      gload16(A + (size_t)(m0 + r) * 512 + t * 64 + sl * 8, smem + buf * 16384 + base);
    }
#pragma unroll
    for (int j = 0; j < BNt / 32; ++j) {   // B: BNt rows x 64 k
      const int base = (wv * (BNt / 32) + j) * 1024;
      const int o = base + lane * 16;
      const int r = o >> 7;
      const int sl = ((o >> 4) & 7) ^ (r & 7);
      gload16(BT + (size_t)(c0 + r) * 512 + t * 64 + sl * 8, smem + 32768 + buf * BBYTES + base);
    }
  };

  stage(0, 0);
  __syncthreads();
  int cur = 0;
  for (int t = 0; t < 8; ++t) {
    if (t < 7) stage(cur ^ 1, t + 1);
    const unsigned short* Ab = (const unsigned short*)(smem + cur * 16384);
    const unsigned short* Bbuf = (const unsigned short*)(smem + 32768 + cur * BBYTES);
    s16x8 af[4][2], bfr[JN][2];
#pragma unroll
    for (int f = 0; f < 4; ++f)
#pragma unroll
      for (int kc = 0; kc < 2; ++kc) {
        const int rr = wm * 64 + f * 16 + n16;
        const int sl = kc * 4 + g;
        af[f][kc] = *(const s16x8*)&Ab[(rr * 128 + ((sl ^ (rr & 7)) * 16)) / 2];
      }
#pragma unroll
    for (int f = 0; f < JN; ++f)
#pragma unroll
      for (int kc = 0; kc < 2; ++kc) {
        const int cc = wn * (BNt / 2) + f * 16 + n16;
        const int sl = kc * 4 + g;
        bfr[f][kc] = *(const s16x8*)&Bbuf[(cc * 128 + ((sl ^ (cc & 7)) * 16)) / 2];
      }
    __builtin_amdgcn_s_setprio(1);
#pragma unroll
    for (int i = 0; i < 4; ++i)
#pragma unroll
      for (int jn = 0; jn < JN; ++jn) {
        acc[i][jn] = __builtin_amdgcn_mfma_f32_16x16x32_bf16(af[i][0], bfr[jn][0], acc[i][jn], 0, 0, 0);
        acc[i][jn] = __builtin_amdgcn_mfma_f32_16x16x32_bf16(af[i][1], bfr[jn][1], acc[i][jn], 0, 0, 0);
      }
    __builtin_amdgcn_s_setprio(0);
    __syncthreads();
    cur ^= 1;
  }

  if (MODE == 0) {
    const int bq = m0 >> 11, nn0 = m0 & 2047;
    if (c0 < 1024) {
      // Q or K: per-lane 2B stores in 32B runs (16 consecutive dk)
#pragma unroll
      for (int i = 0; i < 4; ++i) {
        const int tl0 = wm * 64 + i * 16 + g * 4;
#pragma unroll
        for (int jn = 0; jn < JN; ++jn) {
          const int c = c0 + wn * 64 + jn * 16 + n16;
          if (c < 512) {
            const int h = c >> 6, dk = c & 63;
            unsigned short* qp = qb + (((size_t)bq * 8 + h) * 2048 + nn0 + tl0) * 64 + dk;
#pragma unroll
            for (int r = 0; r < 4; ++r) qp[(size_t)r * 64] = f2bf(acc[i][jn][r] * QSCALE);
          } else {
            const int c2 = c - 512, h = c2 >> 6, dk = c2 & 63;
            unsigned short* kp = kb + (((size_t)bq * 8 + h) * 2048 + nn0 + tl0) * 64 + dk;
#pragma unroll
            for (int r = 0; r < 4; ++r) kp[(size_t)r * 64] = f2bf(acc[i][jn][r]);
          }
        }
      }
    } else {
      // V: re-tile through LDS -> coalesced 16B writes of V^T (B,H,64,N)
      constexpr int SW = 136;   // ushort stride (272B: 16B-aligned rows, bank-spread)
      unsigned short* Ep = (unsigned short*)smem;
#pragma unroll
      for (int i = 0; i < 4; ++i) {
        const int tl0 = wm * 64 + i * 16 + g * 4;
#pragma unroll
        for (int jn = 0; jn < JN; ++jn) {
          const int cl = wn * 64 + jn * 16 + n16;
          ushort4 pk;
          pk.x = f2bf(acc[i][jn][0]); pk.y = f2bf(acc[i][jn][1]);
          pk.z = f2bf(acc[i][jn][2]); pk.w = f2bf(acc[i][jn][3]);
          *(ushort4*)&Ep[cl * SW + (tl0 ^ (((cl >> 3) & 7) << 3))] = pk;
        }
      }
      __syncthreads();
#pragma unroll
      for (int itc = 0; itc < 8; ++itc) {
        const int chunk = itc * 256 + tid;
        const int cl = chunk >> 4, tc = chunk & 15;
        const s16x8 v = *(const s16x8*)&Ep[cl * SW + ((tc * 8) ^ (((cl >> 3) & 7) << 3))];
        const int c2 = c0 + cl - 1024;
        const int h = c2 >> 6, dk = c2 & 63;
        *(s16x8*)(vt + (((size_t)bq * 8 + h) * 64 + dk) * 2048 + nn0 + tc * 8) = v;
      }
    }
  } else {
#pragma unroll
    for (int jn = 0; jn < JN; ++jn) {
      const int c = c0 + wn * (BNt / 2) + jn * 16 + n16;
      const float bc = bias[c];
#pragma unroll
      for (int i = 0; i < 4; ++i) {
        const int tok0 = m0 + wm * 64 + i * 16 + g * 4;
#pragma unroll
        for (int r = 0; r < 4; ++r) {
          float v = acc[i][jn][r] + bc;
          v = v >= 0.f ? v : 0.1f * v;               // LeakyReLU
          outp[(size_t)(tok0 + r) * 512 + c] = v;
        }
      }
    }
  }
}

// ---- flash attention: 8 waves x 16 q-rows (QBLK=128), KVBLK=128 as two
// verified 64x64 sub-tiles per barrier interval -> 16 iterations instead of
// 32 (halved barrier/drain count; tests the barrier-bound hypothesis).
// All per-sub compute paths identical to the verified round-13 structure.
// No softmax stabilizer (log2-domain scores, diagonal keeps l>0).
__global__ __launch_bounds__(512, 4) void attn_kernel(
    const unsigned short* __restrict__ qb, const unsigned short* __restrict__ kb,
    const unsigned short* __restrict__ vt, const unsigned long long* __restrict__ mp,
    unsigned short* __restrict__ ao) {
  __shared__ unsigned short Kl[2][2][4096];  // [buf][sub][m 64][k 64] (swizzled)
  __shared__ unsigned short Vl[2][2][4096];  // [buf][sub][dk 64][m 64]
  __shared__ unsigned short Pl[8][1024];     // per-wave [n 16][m 64]
  const int tid = threadIdx.x, lane = tid & 63, wv = tid >> 6;
  const int g = lane >> 4, n16 = lane & 15;
  // XCD-aware swizzle: 512 blocks, 8 XCDs -> 64 contiguous logical blocks per
  // XCD = 4 (b,h) groups, K/V (512KB/head) resident in its private L2.
  const int sbid = (blockIdx.x & 7) * 64 + (blockIdx.x >> 3);
  const int qt = sbid & 15, bh = sbid >> 4;
  const int b = bh >> 3, h = bh & 7;
  const int n0 = qt * 128 + wv * 16;
  const unsigned short* Qh = qb + (size_t)bh * 2048 * 64;
  const unsigned short* Kh = kb + (size_t)bh * 2048 * 64;
  const unsigned short* Vh = vt + (size_t)bh * 64 * 2048;
  const unsigned long long* mrow = mp + ((size_t)b * 2048 + n0 + n16) * 32;

  // Q fragments (B-operand of swapped QK^T): row n=lane&15, k-contig, pre-scaled
  const s16x8 qf0 = *(const s16x8*)&Qh[(size_t)(n0 + n16) * 64 + g * 8];
  const s16x8 qf1 = *(const s16x8*)&Qh[(size_t)(n0 + n16) * 64 + 32 + g * 8];

  const s16x8 ones = {0x3F80, 0x3F80, 0x3F80, 0x3F80, 0x3F80, 0x3F80, 0x3F80, 0x3F80};

  f32x4 of[4] = {};
  f32x4 acc_l = {};

  unsigned short* Pw = Pl[wv];
  // hoisted P LDS byte offsets (XOR-swizzled)
  int pwo[4], pro[2];
#pragma unroll
  for (int mf = 0; mf < 4; ++mf) {
    int bo = n16 * 128 + mf * 32 + g * 8;
    pwo[mf] = bo ^ ((n16 & 7) << 4);
  }
#pragma unroll
  for (int kc = 0; kc < 2; ++kc) {
    int bo = n16 * 128 + kc * 64 + g * 16;
    pro[kc] = bo ^ ((n16 & 7) << 4);
  }

  // 512 lanes cover each 8KB sub-tile with one 16B load per lane
  auto stage = [&](int buf, int t) {
#pragma unroll
    for (int s = 0; s < 2; ++s) {
      const int base = wv * 1024;
      const int o = base + lane * 16;
      const int r = o >> 7;
      const int sl = ((o >> 4) & 7) ^ (r & 7);    // pre-swizzled logical slot
      gload16(Kh + (size_t)(t * 128 + s * 64 + r) * 64 + sl * 8, (char*)&Kl[buf][s][0] + base);
      gload16(Vh + (size_t)r * 2048 + t * 128 + s * 64 + sl * 8, (char*)&Vl[buf][s][0] + base);
    }
  };

  stage(0, 0);
  unsigned long long wb[2] = {mrow[0], mrow[1]};
  __syncthreads();    // drains vmcnt before any wave reads the tile
  int cur = 0;
  for (int it = 0; it < 16; ++it) {
    if (it < 15) stage(cur ^ 1, it + 1);
    unsigned long long wn0 = 0ull, wn1 = 0ull;
    if (it < 15) { wn0 = mrow[2 * it + 2]; wn1 = mrow[2 * it + 3]; }

#pragma unroll
    for (int sub = 0; sub < 2; ++sub) {
      const unsigned long long wbits = wb[sub];

      // S^T = K · Q : lane holds S[m = 16mf+4g+r][n = n16] (log2 domain)
      f32x4 sc[4] = {};
      __builtin_amdgcn_s_setprio(1);
#pragma unroll
      for (int mf = 0; mf < 4; ++mf) {
        const int ml = mf * 16 + n16;
#pragma unroll
        for (int kc = 0; kc < 2; ++kc) {
          const int sl = kc * 4 + g;
          const s16x8 kf = *(const s16x8*)&Kl[cur][sub][(ml * 128 + ((sl ^ (ml & 7)) * 16)) / 2];
          sc[mf] = __builtin_amdgcn_mfma_f32_16x16x32_bf16(kf, kc ? qf1 : qf0, sc[mf], 0, 0, 0);
        }
      }
      __builtin_amdgcn_s_setprio(0);

      // pre-shift mask word so bit positions are compile-time constants
      const unsigned int wlo = (unsigned int)(wbits >> (g * 4));
      const unsigned int whi = (unsigned int)(wbits >> (32 + g * 4));

      // p = exp2(s), masked via sbfe sign-mask AND (2 VALU/elem), pack bf16
      unsigned int w[8];
#pragma unroll
      for (int mf = 0; mf < 4; ++mf) {
        const unsigned int wsel = ((mf & 2) ? whi : wlo) >> ((mf & 1) * 16);
        float p[4];
#pragma unroll
        for (int r = 0; r < 4; ++r) {
          const unsigned int sm = (unsigned int)__builtin_amdgcn_sbfe((int)wsel, r, 1);
          const float pv = exp2_hw(sc[mf][r]);
          p[r] = __uint_as_float(__float_as_uint(pv) & sm);
        }
        w[mf * 2]     = cvtpk_bf16(p[0], p[1]);
        w[mf * 2 + 1] = cvtpk_bf16(p[2], p[3]);
      }

      // P^T -> per-wave LDS (swizzled), re-fragment as PV A-operand
#pragma unroll
      for (int mf = 0; mf < 4; ++mf) {
        uint2 pk2; pk2.x = w[mf * 2]; pk2.y = w[mf * 2 + 1];
        *(uint2*)((char*)Pw + pwo[mf]) = pk2;
      }
      __builtin_amdgcn_s_setprio(1);
#pragma unroll
      for (int kc = 0; kc < 2; ++kc) {
        const s16x8 pf = *(const s16x8*)((const char*)Pw + pro[kc]);
        acc_l = __builtin_amdgcn_mfma_f32_16x16x32_bf16(pf, ones, acc_l, 0, 0, 0);  // l-sum
#pragma unroll
        for (int df = 0; df < 4; ++df) {
          const int dk = df * 16 + n16;
          const int sl = kc * 4 + g;
          const s16x8 vf = *(const s16x8*)&Vl[cur][sub][(dk * 128 + ((sl ^ (dk & 7)) * 16)) / 2];
          of[df] = __builtin_amdgcn_mfma_f32_16x16x32_bf16(pf, vf, of[df], 0, 0, 0);
        }
      }
      __builtin_amdgcn_s_setprio(0);
    }

    wb[0] = wn0; wb[1] = wn1;
    __syncthreads();   // drains staged loads for buffer cur^1 + guards overwrite
    cur ^= 1;
  }

  float rinv[4];
#pragma unroll
  for (int r = 0; r < 4; ++r) rinv[r] = 1.f / acc_l[r];
#pragma unroll
  for (int df = 0; df < 4; ++df)
#pragma unroll
    for (int r = 0; r < 4; ++r) {
      const int token = b * 2048 + n0 + 4 * g + r;
      ao[(size_t)token * 512 + h * 64 + df * 16 + n16] = f2bf(of[df][r] * rinv[r]);
    }
}

extern "C" void kernel_launch(void* const* d_in, const int* in_sizes, int n_in,
                              void* d_out, int out_size, void* d_ws, size_t ws_size,
                              hipStream_t stream) {
  const float* x = (const float*)d_in[0];
  const void* mask = d_in[1];
  const float* Wqkv = (const float*)d_in[2];
  const float* Wout = (const float*)d_in[3];
  const float* bout = (const float*)d_in[4];
  float* out = (float*)d_out;
  char* ws = (char*)d_ws;

  unsigned short* xb = (unsigned short*)(ws + OFF_XB);
  unsigned short* wqkvT = (unsigned short*)(ws + OFF_WQKVT);
  unsigned short* woutT = (unsigned short*)(ws + OFF_WOUTT);
  unsigned long long* mp = (unsigned long long*)(ws + OFF_MASKP);
  unsigned short* qb = (unsigned short*)(ws + OFF_Q);
  unsigned short* kb = (unsigned short*)(ws + OFF_K);
  unsigned short* vt = (unsigned short*)(ws + OFF_VT);
  unsigned short* ao = (unsigned short*)(ws + OFF_AO);

  prep_kernel<<<3328, 256, 0, stream>>>(x, xb, Wqkv, wqkvT, Wout, woutT,
                                        (const unsigned char*)mask, (const int*)mask, mp);
  gemm128<0, 128><<<768, 256, 0, stream>>>(xb, wqkvT, qb, kb, vt, nullptr, nullptr);
  attn_kernel<<<512, 512, 0, stream>>>(qb, kb, vt, mp, ao);
  gemm128<1, 64><<<512, 256, 0, stream>>>(ao, woutT, nullptr, nullptr, nullptr, bout, out);
}